// Round 1
// baseline (313.686 us; speedup 1.0000x reference)
//
#include <hip/hip_runtime.h>
#include <cmath>

#define N_J   44      // 4 delta + 8 theta + 32 gamma
#define KDIM  128
#define NCLS  5

// ---------------------------------------------------------------------------
// fast tanh: tanh(z) = 1 - 2/(exp(2z)+1), sign-restored. |err| ~1e-7.
__device__ __forceinline__ float fast_tanh(float a) {
    float z = fminf(fabsf(a), 15.0f);
    float e = __expf(2.0f * z);
    float t = 1.0f - 2.0f / (e + 1.0f);
    return copysignf(t, a);
}

// ---------------------------------------------------------------------------
// prep: build W_all^T [44][128] and Wc_eff [44][5] (gamma rows scaled by C)
// into d_ws. Runs every launch (ws is poisoned before timing).
__global__ void hc_prep(const float* __restrict__ Wd, const float* __restrict__ Wt,
                        const float* __restrict__ Wg, const float* __restrict__ Wc,
                        float C, float* __restrict__ ws) {
    int t = threadIdx.x;
    for (int idx = t; idx < N_J * KDIM; idx += 256) {
        int j = idx / KDIM, k = idx % KDIM;
        float v;
        if (j < 4)       v = Wd[k * 4  + j];
        else if (j < 12) v = Wt[k * 8  + (j - 4)];
        else             v = Wg[k * 32 + (j - 12)];
        ws[idx] = v;
    }
    for (int idx = t; idx < N_J * NCLS; idx += 256) {
        int j = idx / NCLS;
        ws[N_J * KDIM + idx] = Wc[idx] * (j >= 12 ? C : 1.0f);
    }
}

// ---------------------------------------------------------------------------
// main: 2 rows per thread; out[r][c] = bc[c] + sum_j tanh(x_r . W_j) * Wce[j][c]
__global__ __launch_bounds__(256) void hc_main(
        const float* __restrict__ x, const float* __restrict__ ws,
        const float* __restrict__ bc, float* __restrict__ out, int nrows) {
    const float4* __restrict__ WT4 = reinterpret_cast<const float4*>(ws); // [44][32]
    const float*  __restrict__ WCE = ws + N_J * KDIM;                     // [44][5]

    const int tid = threadIdx.x;
    const long long base = (long long)blockIdx.x * 512;
    const long long r0 = base + tid;
    const long long r1 = base + 256 + tid;
    const bool ok0 = r0 < nrows, ok1 = r1 < nrows;

    const float4* __restrict__ x40 = reinterpret_cast<const float4*>(x) + r0 * 32;
    const float4* __restrict__ x41 = reinterpret_cast<const float4*>(x) + r1 * 32;

    float acc0[N_J], acc1[N_J];
#pragma unroll
    for (int j = 0; j < N_J; ++j) { acc0[j] = 0.0f; acc1[j] = 0.0f; }

    float4 c0 = {0,0,0,0}, c1 = {0,0,0,0};
    if (ok0) c0 = x40[0];
    if (ok1) c1 = x41[0];

    for (int kq = 0; kq < 32; ++kq) {
        float4 n0 = {0,0,0,0}, n1 = {0,0,0,0};
        if (kq < 31) {                       // prefetch next quad
            if (ok0) n0 = x40[kq + 1];
            if (ok1) n1 = x41[kq + 1];
        }
#pragma unroll
        for (int j = 0; j < N_J; ++j) {
            float4 w = WT4[j * 32 + kq];     // wave-uniform -> scalar/L1
            acc0[j] = fmaf(c0.x, w.x, fmaf(c0.y, w.y,
                       fmaf(c0.z, w.z, fmaf(c0.w, w.w, acc0[j]))));
            acc1[j] = fmaf(c1.x, w.x, fmaf(c1.y, w.y,
                       fmaf(c1.z, w.z, fmaf(c1.w, w.w, acc1[j]))));
        }
        c0 = n0; c1 = n1;
    }

    float b[NCLS];
#pragma unroll
    for (int c = 0; c < NCLS; ++c) b[c] = bc[c];

    if (ok0) {
        float o[NCLS];
#pragma unroll
        for (int c = 0; c < NCLS; ++c) o[c] = b[c];
#pragma unroll
        for (int j = 0; j < N_J; ++j) {
            float t = fast_tanh(acc0[j]);
#pragma unroll
            for (int c = 0; c < NCLS; ++c) o[c] = fmaf(t, WCE[j * NCLS + c], o[c]);
        }
#pragma unroll
        for (int c = 0; c < NCLS; ++c) out[r0 * NCLS + c] = o[c];
    }
    if (ok1) {
        float o[NCLS];
#pragma unroll
        for (int c = 0; c < NCLS; ++c) o[c] = b[c];
#pragma unroll
        for (int j = 0; j < N_J; ++j) {
            float t = fast_tanh(acc1[j]);
#pragma unroll
            for (int c = 0; c < NCLS; ++c) o[c] = fmaf(t, WCE[j * NCLS + c], o[c]);
        }
#pragma unroll
        for (int c = 0; c < NCLS; ++c) out[r1 * NCLS + c] = o[c];
    }
}

// ---------------------------------------------------------------------------
extern "C" void kernel_launch(void* const* d_in, const int* in_sizes, int n_in,
                              void* d_out, int out_size, void* d_ws, size_t ws_size,
                              hipStream_t stream) {
    const float* x  = (const float*)d_in[0];
    const float* Wd = (const float*)d_in[1];
    const float* Wt = (const float*)d_in[2];
    const float* Wg = (const float*)d_in[3];
    const float* Wc = (const float*)d_in[4];
    const float* bc = (const float*)d_in[5];
    float* out = (float*)d_out;
    const int nrows = in_sizes[0] / KDIM;

    // -------- host: closed-form gamma amplitude scale C (data-independent) ---
    // a_g(5) = dr_g * [ (1-dt)^5 + dt * sum_{k=0..4} pac_k (1-dt)^{4-k} ]
    // pac_k = 1 + 0.3 cos(mp_t(k)); mp_t from the 8-oscillator theta recurrence
    // driven by mp_d(k) = circ_mean(k*dt*w_d). All batch-independent.
    const double dt = 0.01, twopi = 6.283185307179586476925286766559;
    double fd[4], ft[8], pht[8];
    for (int i = 0; i < 4; ++i) fd[i] = 1.0 + 3.0 * (double)i / 3.0;   // 1..4
    for (int i = 0; i < 8; ++i) { ft[i] = 4.0 + 4.0 * (double)i / 7.0; pht[i] = 0.0; }
    double Csum = 0.0;
    for (int k = 0; k < 5; ++k) {
        double s = 0.0, c = 0.0;
        for (int i = 0; i < 4; ++i) { double p = twopi * fd[i] * dt * (double)k; s += sin(p); c += cos(p); }
        double mpd = atan2(s * 0.25, c * 0.25);
        double s2 = 0.0, c2 = 0.0;
        for (int i = 0; i < 8; ++i) { s2 += sin(pht[i]); c2 += cos(pht[i]); }
        double mpt = atan2(s2 * 0.125, c2 * 0.125);
        double pac = 1.0 + 0.3 * cos(mpt);
        Csum += pac * pow(1.0 - dt, 4.0 - (double)k);
        for (int i = 0; i < 8; ++i)
            pht[i] += dt * (twopi * ft[i] + 2.0 * sin(mpd - pht[i]));
    }
    const double Cd = pow(1.0 - dt, 5.0) + dt * Csum;
    const float C = (float)Cd;

    hc_prep<<<1, 256, 0, stream>>>(Wd, Wt, Wg, Wc, C, (float*)d_ws);
    const int grid = (nrows + 511) / 512;
    hc_main<<<grid, 256, 0, stream>>>(x, (const float*)d_ws, bc, out, nrows);
}

// Round 2
// 111.769 us; speedup vs baseline: 2.8066x; 2.8066x over previous
//
#include <hip/hip_runtime.h>
#include <cmath>

#define N_J   44      // 4 delta + 8 theta + 32 gamma
#define KDIM  128
#define NCLS  5

// ---------------------------------------------------------------------------
// fast tanh: tanh(z) = 1 - 2/(exp(2z)+1), sign-restored. |err| ~1e-7.
__device__ __forceinline__ float fast_tanh(float a) {
    float z = fminf(fabsf(a), 15.0f);
    float e = __expf(2.0f * z);
    float t = 1.0f - 2.0f / (e + 1.0f);
    return copysignf(t, a);
}

// ---------------------------------------------------------------------------
// prep: build W_all^T [44][128] and Wc_eff [44][5] (gamma rows scaled by C)
// into d_ws. Runs every launch (ws is poisoned before timing).
__global__ void hc_prep(const float* __restrict__ Wd, const float* __restrict__ Wt,
                        const float* __restrict__ Wg, const float* __restrict__ Wc,
                        float C, float* __restrict__ ws) {
    int t = threadIdx.x;
    for (int idx = t; idx < N_J * KDIM; idx += 256) {
        int j = idx / KDIM, k = idx % KDIM;
        float v;
        if (j < 4)       v = Wd[k * 4  + j];
        else if (j < 12) v = Wt[k * 8  + (j - 4)];
        else             v = Wg[k * 32 + (j - 12)];
        ws[idx] = v;
    }
    for (int idx = t; idx < N_J * NCLS; idx += 256) {
        int j = idx / NCLS;
        ws[N_J * KDIM + idx] = Wc[idx] * (j >= 12 ? C : 1.0f);
    }
}

// ---------------------------------------------------------------------------
// main: 1 row per thread. Each lane consumes a full 64B granule (4x float4
// contiguous) per K-step so every fetched byte is used immediately; the next
// 64B chunk is prefetched into a second register buffer while computing.
__global__ __launch_bounds__(256) void hc_main(
        const float* __restrict__ x, const float* __restrict__ ws,
        const float* __restrict__ bc, float* __restrict__ out, int nrows) {
    const float4* __restrict__ WT4 = reinterpret_cast<const float4*>(ws); // [44][32]
    const float*  __restrict__ WCE = ws + N_J * KDIM;                     // [44][5]

    const long long r = (long long)blockIdx.x * 256 + threadIdx.x;
    if (r >= nrows) return;
    const float4* __restrict__ x4 = reinterpret_cast<const float4*>(x) + r * 32;

    float acc[N_J];
#pragma unroll
    for (int j = 0; j < N_J; ++j) acc[j] = 0.0f;

    float4 cur[4], nxt[4];
#pragma unroll
    for (int i = 0; i < 4; ++i) cur[i] = x4[i];

    for (int kb = 0; kb < 8; ++kb) {          // 8 chunks of 16 floats (64B)
        if (kb < 7) {
#pragma unroll
            for (int i = 0; i < 4; ++i) nxt[i] = x4[(kb + 1) * 4 + i];
        }
#pragma unroll
        for (int q = 0; q < 4; ++q) {
            const int kq = kb * 4 + q;
#pragma unroll
            for (int j = 0; j < N_J; ++j) {
                float4 w = WT4[j * 32 + kq];  // wave-uniform -> scalar loads
                acc[j] = fmaf(cur[q].x, w.x, fmaf(cur[q].y, w.y,
                          fmaf(cur[q].z, w.z, fmaf(cur[q].w, w.w, acc[j]))));
            }
        }
#pragma unroll
        for (int i = 0; i < 4; ++i) cur[i] = nxt[i];
    }

    float o[NCLS];
#pragma unroll
    for (int c = 0; c < NCLS; ++c) o[c] = bc[c];
#pragma unroll
    for (int j = 0; j < N_J; ++j) {
        float t = fast_tanh(acc[j]);
#pragma unroll
        for (int c = 0; c < NCLS; ++c) o[c] = fmaf(t, WCE[j * NCLS + c], o[c]);
    }
#pragma unroll
    for (int c = 0; c < NCLS; ++c) out[r * NCLS + c] = o[c];
}

// ---------------------------------------------------------------------------
extern "C" void kernel_launch(void* const* d_in, const int* in_sizes, int n_in,
                              void* d_out, int out_size, void* d_ws, size_t ws_size,
                              hipStream_t stream) {
    const float* x  = (const float*)d_in[0];
    const float* Wd = (const float*)d_in[1];
    const float* Wt = (const float*)d_in[2];
    const float* Wg = (const float*)d_in[3];
    const float* Wc = (const float*)d_in[4];
    const float* bc = (const float*)d_in[5];
    float* out = (float*)d_out;
    const int nrows = in_sizes[0] / KDIM;

    // -------- host: closed-form gamma amplitude scale C (data-independent) ---
    // a_g(5) = dr_g * [ (1-dt)^5 + dt * sum_{k=0..4} pac_k (1-dt)^{4-k} ]
    // pac_k = 1 + 0.3 cos(mp_t(k)); mp_t from the 8-oscillator theta recurrence
    // driven by mp_d(k) = circ_mean(k*dt*w_d). All batch-independent.
    const double dt = 0.01, twopi = 6.283185307179586476925286766559;
    double fd[4], ft[8], pht[8];
    for (int i = 0; i < 4; ++i) fd[i] = 1.0 + 3.0 * (double)i / 3.0;   // 1..4
    for (int i = 0; i < 8; ++i) { ft[i] = 4.0 + 4.0 * (double)i / 7.0; pht[i] = 0.0; }
    double Csum = 0.0;
    for (int k = 0; k < 5; ++k) {
        double s = 0.0, c = 0.0;
        for (int i = 0; i < 4; ++i) { double p = twopi * fd[i] * dt * (double)k; s += sin(p); c += cos(p); }
        double mpd = atan2(s * 0.25, c * 0.25);
        double s2 = 0.0, c2 = 0.0;
        for (int i = 0; i < 8; ++i) { s2 += sin(pht[i]); c2 += cos(pht[i]); }
        double mpt = atan2(s2 * 0.125, c2 * 0.125);
        double pac = 1.0 + 0.3 * cos(mpt);
        Csum += pac * pow(1.0 - dt, 4.0 - (double)k);
        for (int i = 0; i < 8; ++i)
            pht[i] += dt * (twopi * ft[i] + 2.0 * sin(mpd - pht[i]));
    }
    const double Cd = pow(1.0 - dt, 5.0) + dt * Csum;
    const float C = (float)Cd;

    hc_prep<<<1, 256, 0, stream>>>(Wd, Wt, Wg, Wc, C, (float*)d_ws);
    const int grid = (nrows + 255) / 256;
    hc_main<<<grid, 256, 0, stream>>>(x, (const float*)d_ws, bc, out, nrows);
}

// Round 3
// 93.515 us; speedup vs baseline: 3.3544x; 1.1952x over previous
//
#include <hip/hip_runtime.h>
#include <cmath>

#define N_J   44      // 4 delta + 8 theta + 32 gamma
#define KDIM  128
#define NCLS  5
#define NT    3       // n-tiles of 16 (44 padded to 48)
#define WCE_OFF (N_J * KDIM)   // ws offset of padded [48][5] classifier weights

typedef __attribute__((ext_vector_type(8))) short bf16x8;
typedef __attribute__((ext_vector_type(4))) float f32x4;

// ---------------------------------------------------------------------------
__device__ __forceinline__ float fast_tanh(float a) {
    float z = fminf(fabsf(a), 15.0f);
    float e = __expf(2.0f * z);
    float t = 1.0f - 2.0f / (e + 1.0f);
    return copysignf(t, a);
}

// round-to-nearest-even f32 -> bf16 bits
__device__ __forceinline__ short bf16_rne(float f) {
    unsigned u = __builtin_bit_cast(unsigned, f);
    unsigned r = (u + 0x7fffu + ((u >> 16) & 1u)) >> 16;
    return (short)r;
}
__device__ __forceinline__ float bf16_to_f32(short s) {
    unsigned u = ((unsigned)(unsigned short)s) << 16;
    return __builtin_bit_cast(float, u);
}

// ---------------------------------------------------------------------------
// prep: W_all^T [44][128] at ws[0..5632), Wc_eff padded [48][5] (gamma rows
// scaled by C, rows 44..47 zero) at ws[5632..5872).
__global__ void hc_prep(const float* __restrict__ Wd, const float* __restrict__ Wt,
                        const float* __restrict__ Wg, const float* __restrict__ Wc,
                        float C, float* __restrict__ ws) {
    int t = threadIdx.x;
    for (int idx = t; idx < N_J * KDIM; idx += 256) {
        int j = idx / KDIM, k = idx % KDIM;
        float v;
        if (j < 4)       v = Wd[k * 4  + j];
        else if (j < 12) v = Wt[k * 8  + (j - 4)];
        else             v = Wg[k * 32 + (j - 12)];
        ws[idx] = v;
    }
    for (int idx = t; idx < 48 * NCLS; idx += 256) {
        int j = idx / NCLS;
        float v = (j < N_J) ? Wc[idx] * (j >= 12 ? C : 1.0f) : 0.0f;
        ws[WCE_OFF + idx] = v;
    }
}

// ---------------------------------------------------------------------------
// main: each wave computes 16-row tiles via mfma_f32_16x16x32_bf16.
// A = x (split hi+lo bf16 for f32-grade accuracy), B = W^T frags in VGPRs.
__global__ __launch_bounds__(256) void hc_main(
        const float* __restrict__ x, const float* __restrict__ ws,
        const float* __restrict__ bc, float* __restrict__ out, int nrows) {
    const int lane = threadIdx.x & 63;
    const int n    = lane & 15;        // A-row-in-tile / B-col / C-col
    const int g    = lane >> 4;        // k-group (and C row-group)
    const long long wave   = ((long long)blockIdx.x * blockDim.x + threadIdx.x) >> 6;
    const long long nwaves = ((long long)gridDim.x * blockDim.x) >> 6;
    const long long ntiles = (nrows + 15) / 16;

    // ---- B fragments: 3 n-tiles x 4 k-blocks, bf16, held in VGPRs ---------
    bf16x8 Bf[NT][4];
#pragma unroll
    for (int t = 0; t < NT; ++t) {
        const int j = t * 16 + n;
        const bool jv = (j < N_J);
#pragma unroll
        for (int kb = 0; kb < 4; ++kb) {
            const int k0 = kb * 32 + g * 8;
            float4 q0 = {0,0,0,0}, q1 = {0,0,0,0};
            if (jv) {
                const float4* wp = reinterpret_cast<const float4*>(ws + j * KDIM + k0);
                q0 = wp[0]; q1 = wp[1];
            }
            Bf[t][kb][0] = bf16_rne(q0.x); Bf[t][kb][1] = bf16_rne(q0.y);
            Bf[t][kb][2] = bf16_rne(q0.z); Bf[t][kb][3] = bf16_rne(q0.w);
            Bf[t][kb][4] = bf16_rne(q1.x); Bf[t][kb][5] = bf16_rne(q1.y);
            Bf[t][kb][6] = bf16_rne(q1.z); Bf[t][kb][7] = bf16_rne(q1.w);
        }
    }

    // ---- classifier weights for this lane's j-columns ----------------------
    float wce[NT][NCLS];
#pragma unroll
    for (int t = 0; t < NT; ++t)
#pragma unroll
        for (int c = 0; c < NCLS; ++c)
            wce[t][c] = ws[WCE_OFF + (t * 16 + n) * NCLS + c];
    const float bcv = bc[n < NCLS ? n : 0];

    for (long long tile = wave; tile < ntiles; tile += nwaves) {
        const long long rowb = tile * 16;
        const long long row  = rowb + n;
        const bool rok = (row < (long long)nrows);

        // ---- load A: this lane's 32 floats (row `row`, k = g*8 + kb*32 ..+8)
        float4 raw[8];
        const float4* xp = reinterpret_cast<const float4*>(x) + row * 32 + g * 2;
#pragma unroll
        for (int kb = 0; kb < 4; ++kb) {
            raw[2*kb]     = rok ? xp[kb * 8]     : float4{0,0,0,0};
            raw[2*kb + 1] = rok ? xp[kb * 8 + 1] : float4{0,0,0,0};
        }

        f32x4 acc[NT];
#pragma unroll
        for (int t = 0; t < NT; ++t) acc[t] = f32x4{0.0f, 0.0f, 0.0f, 0.0f};

#pragma unroll
        for (int kb = 0; kb < 4; ++kb) {
            float f[8] = { raw[2*kb].x, raw[2*kb].y, raw[2*kb].z, raw[2*kb].w,
                           raw[2*kb+1].x, raw[2*kb+1].y, raw[2*kb+1].z, raw[2*kb+1].w };
            bf16x8 ah, al;
#pragma unroll
            for (int i = 0; i < 8; ++i) {
                short h = bf16_rne(f[i]);
                ah[i] = h;
                al[i] = bf16_rne(f[i] - bf16_to_f32(h));   // exact residual, re-rounded
            }
#pragma unroll
            for (int t = 0; t < NT; ++t) {
                acc[t] = __builtin_amdgcn_mfma_f32_16x16x32_bf16(ah, Bf[t][kb], acc[t], 0, 0, 0);
                acc[t] = __builtin_amdgcn_mfma_f32_16x16x32_bf16(al, Bf[t][kb], acc[t], 0, 0, 0);
            }
        }

        // ---- epilogue: tanh, per-lane classifier partials, 16-lane reduce --
        // lane holds C[row = g*4 + r][col j = t*16 + n] in acc[t][r]
        float part[4][NCLS];
#pragma unroll
        for (int r = 0; r < 4; ++r) {
            float t0 = fast_tanh(acc[0][r]);
            float t1 = fast_tanh(acc[1][r]);
            float t2 = fast_tanh(acc[2][r]);
#pragma unroll
            for (int c = 0; c < NCLS; ++c)
                part[r][c] = fmaf(t0, wce[0][c], fmaf(t1, wce[1][c], t2 * wce[2][c]));
        }
#pragma unroll
        for (int m = 1; m <= 8; m <<= 1)
#pragma unroll
            for (int r = 0; r < 4; ++r)
#pragma unroll
                for (int c = 0; c < NCLS; ++c)
                    part[r][c] += __shfl_xor(part[r][c], m, 16);

        // lanes with n < 5 write class n of rows rowb + g*4 + r  (80B/group)
#pragma unroll
        for (int r = 0; r < 4; ++r) {
            float o = part[r][0];
            o = (n == 1) ? part[r][1] : o;
            o = (n == 2) ? part[r][2] : o;
            o = (n == 3) ? part[r][3] : o;
            o = (n == 4) ? part[r][4] : o;
            const long long ro = rowb + g * 4 + r;
            if (n < NCLS && ro < (long long)nrows)
                out[ro * NCLS + n] = o + bcv;
        }
    }
}

// ---------------------------------------------------------------------------
extern "C" void kernel_launch(void* const* d_in, const int* in_sizes, int n_in,
                              void* d_out, int out_size, void* d_ws, size_t ws_size,
                              hipStream_t stream) {
    const float* x  = (const float*)d_in[0];
    const float* Wd = (const float*)d_in[1];
    const float* Wt = (const float*)d_in[2];
    const float* Wg = (const float*)d_in[3];
    const float* Wc = (const float*)d_in[4];
    const float* bc = (const float*)d_in[5];
    float* out = (float*)d_out;
    const int nrows = in_sizes[0] / KDIM;

    // -------- host: closed-form gamma amplitude scale C (data-independent) ---
    const double dt = 0.01, twopi = 6.283185307179586476925286766559;
    double fd[4], ft[8], pht[8];
    for (int i = 0; i < 4; ++i) fd[i] = 1.0 + 3.0 * (double)i / 3.0;   // 1..4
    for (int i = 0; i < 8; ++i) { ft[i] = 4.0 + 4.0 * (double)i / 7.0; pht[i] = 0.0; }
    double Csum = 0.0;
    for (int k = 0; k < 5; ++k) {
        double s = 0.0, c = 0.0;
        for (int i = 0; i < 4; ++i) { double p = twopi * fd[i] * dt * (double)k; s += sin(p); c += cos(p); }
        double mpd = atan2(s * 0.25, c * 0.25);
        double s2 = 0.0, c2 = 0.0;
        for (int i = 0; i < 8; ++i) { s2 += sin(pht[i]); c2 += cos(pht[i]); }
        double mpt = atan2(s2 * 0.125, c2 * 0.125);
        double pac = 1.0 + 0.3 * cos(mpt);
        Csum += pac * pow(1.0 - dt, 4.0 - (double)k);
        for (int i = 0; i < 8; ++i)
            pht[i] += dt * (twopi * ft[i] + 2.0 * sin(mpd - pht[i]));
    }
    const double Cd = pow(1.0 - dt, 5.0) + dt * Csum;
    const float C = (float)Cd;

    hc_prep<<<1, 256, 0, stream>>>(Wd, Wt, Wg, Wc, C, (float*)d_ws);
    hc_main<<<2048, 256, 0, stream>>>(x, (const float*)d_ws, bc, out, nrows);
}